// Round 8
// baseline (232.447 us; speedup 1.0000x reference)
//
#include <hip/hip_runtime.h>

#define N_E 10000
#define N_KC 2000
#define KPAD 2048
#define ALPHA 0.2f

typedef __attribute__((ext_vector_type(8))) short short8;
typedef __attribute__((ext_vector_type(4))) float f32x4;

// ---- static device scratch (fully rewritten every call) ----
__device__ float g_w1a1[256];
__device__ float g_t[KPAD];
__device__ unsigned g_bm[N_E * 64];                                // 2.56 MB
__device__ __align__(16) unsigned short g_W1T_pk[16 * 8 * 512];    // B: W1^T
__device__ __align__(16) unsigned short g_ET_pk[16 * 8 * 512];     // B: E^T
__device__ __align__(16) unsigned short g_rdw_pk[16 * 16 * 512];   // B: rd_w
__device__ __align__(16) unsigned short g_kcWh_pk[16 * 64 * 512];  // B: kcWh^T

__device__ __forceinline__ unsigned short f2bf(float f) {
  union { float f; unsigned int u; } v; v.f = f;
  unsigned int r = v.u + 0x7FFFu + ((v.u >> 16) & 1u);
  return (unsigned short)(r >> 16);
}

__device__ __forceinline__ void cvt_store4(float4 v, unsigned short* dst) {
  ushort4 o;
  o.x = f2bf(v.x); o.y = f2bf(v.y); o.z = f2bf(v.z); o.w = f2bf(v.w);
  *reinterpret_cast<ushort4*>(dst) = o;
}

// ---- merged prep: adj bit-pack + weight packing + w1a1 + zero pads ----
__global__ __launch_bounds__(256) void prep_pack_kernel(
    const int* __restrict__ adj, const float* __restrict__ W1,
    const float* __restrict__ E, const float* __restrict__ a,
    const float* __restrict__ rd_w) {
  int b = blockIdx.x, tid = threadIdx.x;
  if (b < 2500) {  // adj -> bitmask: id = row*64 + word
    int id = b * 256 + tid;
    int row = id >> 6, wd = id & 63;
    const int* p = adj + (size_t)row * 2000 + wd * 32;
    unsigned m = 0;
    int nq = (wd < 62) ? 8 : ((wd == 62) ? 4 : 0);
    for (int q = 0; q < nq; ++q) {
      int4 v = *(const int4*)(p + q * 4);
      unsigned mm = (v.x > 0 ? 1u : 0u) | (v.y > 0 ? 2u : 0u) |
                    (v.z > 0 ? 4u : 0u) | (v.w > 0 ? 8u : 0u);
      m |= mm << (q * 4);
    }
    g_bm[(size_t)row * 64 + wd] = m;
  } else if (b < 2532) {  // rd_w -> packed B (ct 16 x kt 16)
#pragma unroll
    for (int s2 = 0; s2 < 2; ++s2) {
      int sId = (b - 2500) * 512 + tid + s2 * 256;
      int ct = sId >> 10, rem = sId & 1023;
      int kt = rem >> 6, lane = rem & 63;
      int g = lane >> 4, r = lane & 15;
      const float* src = rd_w + (size_t)(ct * 16 + r) * 512 + kt * 32 + g * 8;
      unsigned short* dst = g_rdw_pk + (size_t)sId * 8;
      cvt_store4(*(const float4*)src, dst);
      cvt_store4(*(const float4*)(src + 4), dst + 4);
    }
  } else if (b < 2548) {  // W1^T -> packed B
#pragma unroll
    for (int s2 = 0; s2 < 2; ++s2) {
      int sId = (b - 2532) * 512 + tid + s2 * 256;
      int ct = sId >> 9, rem = sId & 511;
      int kt = rem >> 6, lane = rem & 63;
      int g = lane >> 4, r = lane & 15;
      int col = ct * 16 + r, k = kt * 32 + g * 8;
      unsigned short* dst = g_W1T_pk + (size_t)sId * 8;
      ushort4 o0, o1;
      o0.x = f2bf(W1[(k + 0) * 256 + col]); o0.y = f2bf(W1[(k + 1) * 256 + col]);
      o0.z = f2bf(W1[(k + 2) * 256 + col]); o0.w = f2bf(W1[(k + 3) * 256 + col]);
      o1.x = f2bf(W1[(k + 4) * 256 + col]); o1.y = f2bf(W1[(k + 5) * 256 + col]);
      o1.z = f2bf(W1[(k + 6) * 256 + col]); o1.w = f2bf(W1[(k + 7) * 256 + col]);
      *(ushort4*)dst = o0; *(ushort4*)(dst + 4) = o1;
    }
  } else if (b < 2564) {  // E^T -> packed B
#pragma unroll
    for (int s2 = 0; s2 < 2; ++s2) {
      int sId = (b - 2548) * 512 + tid + s2 * 256;
      int ct = sId >> 9, rem = sId & 511;
      int kt = rem >> 6, lane = rem & 63;
      int g = lane >> 4, r = lane & 15;
      int col = ct * 16 + r, k = kt * 32 + g * 8;
      unsigned short* dst = g_ET_pk + (size_t)sId * 8;
      ushort4 o0, o1;
      o0.x = f2bf(E[(k + 0) * 256 + col]); o0.y = f2bf(E[(k + 1) * 256 + col]);
      o0.z = f2bf(E[(k + 2) * 256 + col]); o0.w = f2bf(E[(k + 3) * 256 + col]);
      o1.x = f2bf(E[(k + 4) * 256 + col]); o1.y = f2bf(E[(k + 5) * 256 + col]);
      o1.z = f2bf(E[(k + 6) * 256 + col]); o1.w = f2bf(E[(k + 7) * 256 + col]);
      *(ushort4*)dst = o0; *(ushort4*)(dst + 4) = o1;
    }
  } else if (b == 2564) {  // w1a1
    float acc = 0.f;
    for (int q = 0; q < 64; ++q) {
      float4 wv = *(const float4*)(W1 + (size_t)tid * 256 + q * 4);
      float4 a4 = *(const float4*)(a + q * 4);
      acc += wv.x * a4.x + wv.y * a4.y + wv.z * a4.z + wv.w * a4.w;
    }
    g_w1a1[tid] = acc;
  } else {  // zero pads: kcWh kTiles 62,63 + g_t tail
    for (int idx = tid; idx < 16 * 2 * 512; idx += 256) {
      int ct = idx >> 10, rem = idx & 1023;
      int kt = 62 + (rem >> 9), off = rem & 511;
      g_kcWh_pk[((size_t)ct * 64 + kt) * 512 + off] = 0;
    }
    if (tid < 48) g_t[2000 + tid] = 0.f;
  }
}

// ---- kcWh^T via MFMA (A from f32 kc_h on the fly) + fused t = kcWh@a2 ----
__global__ __launch_bounds__(256) void kc_mfma_kernel(
    const float* __restrict__ kc_h, const float* __restrict__ a) {
  __shared__ float tred[4][4][4];  // [wave][g][q]
  int tid = threadIdx.x, lane = tid & 63, w = tid >> 6;
  int r = lane & 15, g = lane >> 4;
  int j0 = blockIdx.x * 16;
  f32x4 acc[4] = {{0.f,0.f,0.f,0.f},{0.f,0.f,0.f,0.f},
                  {0.f,0.f,0.f,0.f},{0.f,0.f,0.f,0.f}};
  for (int kk = 0; kk < 8; ++kk) {
    int k = kk * 32 + g * 8;
    const float* src = kc_h + (size_t)(j0 + r) * 256 + k;
    float4 x0 = *(const float4*)src, x1 = *(const float4*)(src + 4);
    short8 af = {(short)f2bf(x0.x), (short)f2bf(x0.y), (short)f2bf(x0.z),
                 (short)f2bf(x0.w), (short)f2bf(x1.x), (short)f2bf(x1.y),
                 (short)f2bf(x1.z), (short)f2bf(x1.w)};
#pragma unroll
    for (int n = 0; n < 4; ++n) {
      short8 bf = *(const short8*)(g_W1T_pk + ((size_t)(w * 4 + n) * 8 + kk) *
                                                  512 + lane * 8);
      acc[n] = __builtin_amdgcn_mfma_f32_16x16x32_bf16(af, bf, acc[n], 0, 0, 0);
    }
  }
  // packed store of kcWh^T
  int j = j0 + g * 4;
  int kt = j >> 5, lsub = ((j >> 3) & 3) * 16 + r, sub = (g & 1) * 4;
#pragma unroll
  for (int n = 0; n < 4; ++n) {
    int ct = w * 4 + n;
    ushort4 o;
    o.x = f2bf(acc[n][0]); o.y = f2bf(acc[n][1]);
    o.z = f2bf(acc[n][2]); o.w = f2bf(acc[n][3]);
    *reinterpret_cast<ushort4*>(
        g_kcWh_pk + ((size_t)ct * 64 + kt) * 512 + lsub * 8 + sub) = o;
  }
  // fused t: t[j] = sum_o kcWh[j][o] * a2[o]
  float a2v[4];
#pragma unroll
  for (int n = 0; n < 4; ++n) a2v[n] = a[256 + w * 64 + n * 16 + r];
  float tp[4];
#pragma unroll
  for (int q = 0; q < 4; ++q)
    tp[q] = acc[0][q] * a2v[0] + acc[1][q] * a2v[1] + acc[2][q] * a2v[2] +
            acc[3][q] * a2v[3];
#pragma unroll
  for (int off = 1; off < 16; off <<= 1)
#pragma unroll
    for (int q = 0; q < 4; ++q) tp[q] += __shfl_xor(tp[q], off, 64);
  if (r == 0)
#pragma unroll
    for (int q = 0; q < 4; ++q) tred[w][g][q] = tp[q];
  __syncthreads();
  if (tid < 16)
    g_t[j0 + tid] = tred[0][tid >> 2][tid & 3] + tred[1][tid >> 2][tid & 3] +
                    tred[2][tid >> 2][tid & 3] + tred[3][tid >> 2][tid & 3];
}

// ---- main: s + P-gen (bitmask, LDS) + 3 MFMA GEMMs, pipelined ----
#define PST 280
#define FST 536
#define BMST 65
__global__ __launch_bounds__(512, 6) void main_kernel(
    const float* __restrict__ exh, const float* __restrict__ rd_b,
    float* __restrict__ out) {
  __shared__ float t_s[KPAD];
  __shared__ unsigned bm_s[16 * BMST];
  __shared__ __align__(16) unsigned short p_s[2][16 * PST];
  __shared__ __align__(16) unsigned short feat_s[16 * FST];  // union w/ exh frags
  __shared__ float ds_part[8][16];
  __shared__ float red16[16];

  int tid = threadIdx.x;
  int w = tid >> 6, lane = tid & 63;
  int r = lane & 15, g = lane >> 4;
  int i0 = blockIdx.x * 16;
  unsigned short* exh_pk_s = feat_s;  // [kt*512 + lane*8], 8 KB

  // phase 0: stage t, bitmask, exh fragments; compute s
  for (int q = tid; q < KPAD / 4; q += 512)
    ((float4*)t_s)[q] = ((const float4*)g_t)[q];
  for (int q = tid; q < 16 * 64; q += 512) {
    int rr = q >> 6, wd = q & 63;
    bm_s[rr * BMST + wd] = g_bm[(size_t)(i0 + rr) * 64 + wd];
  }
  {
    const float* xsrc = exh + (size_t)(i0 + r) * 256 + w * 32 + g * 8;
    float4 x0 = *(const float4*)xsrc, x1 = *(const float4*)(xsrc + 4);
    unsigned short* dst = exh_pk_s + w * 512 + lane * 8;
    cvt_store4(x0, dst); cvt_store4(x1, dst + 4);
    const float* wsrc = g_w1a1 + w * 32 + g * 8;
    float4 w0 = *(const float4*)wsrc, w1 = *(const float4*)(wsrc + 4);
    float sp = x0.x * w0.x + x0.y * w0.y + x0.z * w0.z + x0.w * w0.w +
               x1.x * w1.x + x1.y * w1.y + x1.z * w1.z + x1.w * w1.w;
    sp += __shfl_xor(sp, 16, 64);
    sp += __shfl_xor(sp, 32, 64);
    if (lane < 16) ds_part[w][lane] = sp;
  }
  __syncthreads();
  if (tid < 16) {
    float sv = 0.f;
#pragma unroll
    for (int ww = 0; ww < 8; ++ww) sv += ds_part[ww][tid];
    red16[tid] = sv;
  }
  __syncthreads();
  float sv = red16[r];

  f32x4 accP[2] = {{0.f,0.f,0.f,0.f},{0.f,0.f,0.f,0.f}};
  float dsum = 0.f;

  auto gen = [&](int c) {
    int kk = c * 8 + w;
    int4 pk = {0, 0, 0, 0};
    if (kk < 63) {  // wave-uniform; invalid cols masked by bitmask + zero t pad
      int c0 = kk * 32 + g * 8;
      unsigned mb = (bm_s[r * BMST + kk] >> (g * 8)) & 0xFFu;
      float4 t0 = *(const float4*)(t_s + c0);
      float4 t1 = *(const float4*)(t_s + c0 + 4);
      float tv[8] = {t0.x, t0.y, t0.z, t0.w, t1.x, t1.y, t1.z, t1.w};
      unsigned ub[8];
#pragma unroll
      for (int j = 0; j < 8; ++j) {
        float x = sv + tv[j];
        float lx = fmaxf(x, ALPHA * x);
        float pv = ((mb >> j) & 1u) ? __expf(lx) : 0.f;
        dsum += pv;
        ub[j] = __float_as_uint(pv) + 0x8000u;
      }
      pk.x = (int)((ub[0] >> 16) | (ub[1] & 0xFFFF0000u));
      pk.y = (int)((ub[2] >> 16) | (ub[3] & 0xFFFF0000u));
      pk.z = (int)((ub[4] >> 16) | (ub[5] & 0xFFFF0000u));
      pk.w = (int)((ub[6] >> 16) | (ub[7] & 0xFFFF0000u));
    }
    *(int4*)&p_s[c & 1][r * PST + w * 32 + g * 8] = pk;
  };

  auto mfma_chunk = [&](int c) {
    const unsigned short* pb = p_s[c & 1];
    const unsigned short* bb0 =
        g_kcWh_pk + ((size_t)(w * 2 + 0) * 64 + c * 8) * 512 + lane * 8;
    const unsigned short* bb1 =
        g_kcWh_pk + ((size_t)(w * 2 + 1) * 64 + c * 8) * 512 + lane * 8;
    short8 af = *(const short8*)&pb[r * PST + g * 8];
    short8 b0 = *(const short8*)bb0;
    short8 b1 = *(const short8*)bb1;
#pragma unroll
    for (int u = 0; u < 8; ++u) {
      short8 naf = af, nb0 = b0, nb1 = b1;
      if (u < 7) {  // prefetch next u
        naf = *(const short8*)&pb[r * PST + (u + 1) * 32 + g * 8];
        nb0 = *(const short8*)(bb0 + (u + 1) * 512);
        nb1 = *(const short8*)(bb1 + (u + 1) * 512);
      }
      accP[0] = __builtin_amdgcn_mfma_f32_16x16x32_bf16(af, b0, accP[0], 0, 0, 0);
      accP[1] = __builtin_amdgcn_mfma_f32_16x16x32_bf16(af, b1, accP[1], 0, 0, 0);
      af = naf; b0 = nb0; b1 = nb1;
    }
  };

  gen(0);
  __syncthreads();
  for (int c = 1; c < 8; ++c) {
    gen(c);
    mfma_chunk(c - 1);
    __syncthreads();
  }
  mfma_chunk(7);

  dsum += __shfl_xor(dsum, 16, 64);
  dsum += __shfl_xor(dsum, 32, 64);
  if (lane < 16) ds_part[w][lane] = dsum;

  // ex_Eh GEMM (A frags from LDS, B packed)
  f32x4 accE[2] = {{0.f,0.f,0.f,0.f},{0.f,0.f,0.f,0.f}};
#pragma unroll
  for (int kk = 0; kk < 8; ++kk) {
    short8 af = *(const short8*)(exh_pk_s + kk * 512 + lane * 8);
#pragma unroll
    for (int n = 0; n < 2; ++n) {
      short8 bf = *(const short8*)(g_ET_pk + ((size_t)(w * 2 + n) * 8 + kk) *
                                                 512 + lane * 8);
      accE[n] = __builtin_amdgcn_mfma_f32_16x16x32_bf16(af, bf, accE[n], 0, 0, 0);
    }
  }
  __syncthreads();  // exh frags consumed; ds_part complete
  if (tid < 16) {
    float s = 0.f;
#pragma unroll
    for (int ww = 0; ww < 8; ++ww) s += ds_part[ww][tid];
    red16[tid] = 1.f / fmaxf(s, 1e-30f);
  }
  __syncthreads();

  // feat = [new_kc | new_kc * ex_Eh] (overwrites exh frag region)
  int c0e = w * 32;
#pragma unroll
  for (int n = 0; n < 2; ++n) {
    int col = c0e + n * 16 + r;
#pragma unroll
    for (int q = 0; q < 4; ++q) {
      int row = g * 4 + q;
      float nk = accP[n][q] * red16[row];
      feat_s[row * FST + col] = f2bf(nk);
      feat_s[row * FST + 256 + col] = f2bf(nk * accE[n][q]);
    }
  }
  __syncthreads();

  // epilogue GEMM: feat(16x512) @ rd_w^T + bias, ELU
  f32x4 accO[2] = {{0.f,0.f,0.f,0.f},{0.f,0.f,0.f,0.f}};
#pragma unroll
  for (int kk = 0; kk < 16; ++kk) {
    int k = kk * 32 + g * 8;
    short8 af = *(const short8*)&feat_s[r * FST + k];
#pragma unroll
    for (int n = 0; n < 2; ++n) {
      short8 bf = *(const short8*)(g_rdw_pk + ((size_t)(w * 2 + n) * 16 + kk) *
                                                  512 + lane * 8);
      accO[n] = __builtin_amdgcn_mfma_f32_16x16x32_bf16(af, bf, accO[n], 0, 0, 0);
    }
  }
#pragma unroll
  for (int n = 0; n < 2; ++n) {
    int col = c0e + n * 16 + r;
    float bias = rd_b[col];
#pragma unroll
    for (int q = 0; q < 4; ++q) {
      int row = g * 4 + q;
      float x = accO[n][q] + bias;
      float res = x > 0.f ? x : (__expf(x) - 1.f);
      out[(size_t)(i0 + row) * 256 + col] = res;
    }
  }
}

extern "C" void kernel_launch(void* const* d_in, const int* in_sizes, int n_in,
                              void* d_out, int out_size, void* d_ws,
                              size_t ws_size, hipStream_t stream) {
  const float* exh  = (const float*)d_in[0];
  const float* kc_h = (const float*)d_in[1];
  const int*   adj  = (const int*)d_in[2];
  const float* W1   = (const float*)d_in[3];
  const float* E    = (const float*)d_in[4];
  const float* a    = (const float*)d_in[5];
  const float* rd_w = (const float*)d_in[6];
  const float* rd_b = (const float*)d_in[7];
  float* out = (float*)d_out;

  prep_pack_kernel<<<2566, 256, 0, stream>>>(adj, W1, E, a, rd_w);
  kc_mfma_kernel<<<N_KC / 16, 256, 0, stream>>>(kc_h, a);
  main_kernel<<<N_E / 16, 512, 0, stream>>>(exh, rd_b, out);
}

// Round 9
// 183.859 us; speedup vs baseline: 1.2643x; 1.2643x over previous
//
#include <hip/hip_runtime.h>

#define N_E 10000
#define N_KC 2000
#define ALPHA 0.2f

typedef __attribute__((ext_vector_type(8))) short short8;
typedef __attribute__((ext_vector_type(4))) float f32x4;

// ---- static device scratch (fully rewritten every call) ----
__device__ float g_w1a1[256];
__device__ float g_t[2048];
__device__ __align__(16) unsigned short g_W1T_pk[16 * 8 * 512];    // B: W1^T
__device__ __align__(16) unsigned short g_ET_pk[16 * 8 * 512];     // B: E^T
__device__ __align__(16) unsigned short g_rdw_pk[16 * 16 * 512];   // B: rd_w
__device__ __align__(16) unsigned short g_kcWh_pk[16 * 64 * 512];  // B: kcWh^T

__device__ __forceinline__ unsigned short f2bf(float f) {
  union { float f; unsigned int u; } v; v.f = f;
  unsigned int r = v.u + 0x7FFFu + ((v.u >> 16) & 1u);
  return (unsigned short)(r >> 16);
}

__device__ __forceinline__ void cvt_store4(float4 v, unsigned short* dst) {
  ushort4 o;
  o.x = f2bf(v.x); o.y = f2bf(v.y); o.z = f2bf(v.z); o.w = f2bf(v.w);
  *reinterpret_cast<ushort4*>(dst) = o;
}

// ---- prep: weight packing + w1a1 + zero pads (66 blocks, tiny) ----
__global__ __launch_bounds__(256) void prep_kernel(
    const float* __restrict__ W1, const float* __restrict__ E,
    const float* __restrict__ a, const float* __restrict__ rd_w) {
  int b = blockIdx.x, tid = threadIdx.x;
  if (b < 32) {  // rd_w -> packed B (ct 16 x kt 16)
#pragma unroll
    for (int s2 = 0; s2 < 2; ++s2) {
      int sId = b * 512 + tid + s2 * 256;
      int ct = sId >> 10, rem = sId & 1023;
      int kt = rem >> 6, lane = rem & 63;
      int g = lane >> 4, r = lane & 15;
      const float* src = rd_w + (size_t)(ct * 16 + r) * 512 + kt * 32 + g * 8;
      unsigned short* dst = g_rdw_pk + (size_t)sId * 8;
      cvt_store4(*(const float4*)src, dst);
      cvt_store4(*(const float4*)(src + 4), dst + 4);
    }
  } else if (b < 48) {  // W1^T -> packed B (ct 16 x kt 8)
#pragma unroll
    for (int s2 = 0; s2 < 2; ++s2) {
      int sId = (b - 32) * 512 + tid + s2 * 256;
      int ct = sId >> 9, rem = sId & 511;
      int kt = rem >> 6, lane = rem & 63;
      int g = lane >> 4, r = lane & 15;
      int col = ct * 16 + r, k = kt * 32 + g * 8;
      unsigned short* dst = g_W1T_pk + (size_t)sId * 8;
      ushort4 o0, o1;
      o0.x = f2bf(W1[(k + 0) * 256 + col]); o0.y = f2bf(W1[(k + 1) * 256 + col]);
      o0.z = f2bf(W1[(k + 2) * 256 + col]); o0.w = f2bf(W1[(k + 3) * 256 + col]);
      o1.x = f2bf(W1[(k + 4) * 256 + col]); o1.y = f2bf(W1[(k + 5) * 256 + col]);
      o1.z = f2bf(W1[(k + 6) * 256 + col]); o1.w = f2bf(W1[(k + 7) * 256 + col]);
      *(ushort4*)dst = o0; *(ushort4*)(dst + 4) = o1;
    }
  } else if (b < 64) {  // E^T -> packed B
#pragma unroll
    for (int s2 = 0; s2 < 2; ++s2) {
      int sId = (b - 48) * 512 + tid + s2 * 256;
      int ct = sId >> 9, rem = sId & 511;
      int kt = rem >> 6, lane = rem & 63;
      int g = lane >> 4, r = lane & 15;
      int col = ct * 16 + r, k = kt * 32 + g * 8;
      unsigned short* dst = g_ET_pk + (size_t)sId * 8;
      ushort4 o0, o1;
      o0.x = f2bf(E[(k + 0) * 256 + col]); o0.y = f2bf(E[(k + 1) * 256 + col]);
      o0.z = f2bf(E[(k + 2) * 256 + col]); o0.w = f2bf(E[(k + 3) * 256 + col]);
      o1.x = f2bf(E[(k + 4) * 256 + col]); o1.y = f2bf(E[(k + 5) * 256 + col]);
      o1.z = f2bf(E[(k + 6) * 256 + col]); o1.w = f2bf(E[(k + 7) * 256 + col]);
      *(ushort4*)dst = o0; *(ushort4*)(dst + 4) = o1;
    }
  } else if (b == 64) {  // w1a1
    float acc = 0.f;
    for (int q = 0; q < 64; ++q) {
      float4 wv = *(const float4*)(W1 + (size_t)tid * 256 + q * 4);
      float4 a4 = *(const float4*)(a + q * 4);
      acc += wv.x * a4.x + wv.y * a4.y + wv.z * a4.z + wv.w * a4.w;
    }
    g_w1a1[tid] = acc;
  } else {  // zero pads: kcWh kTiles 62,63 + g_t tail
    for (int idx = tid; idx < 16 * 2 * 512; idx += 256) {
      int ct = idx >> 10, rem = idx & 1023;
      int kt = 62 + (rem >> 9), off = rem & 511;
      g_kcWh_pk[((size_t)ct * 64 + kt) * 512 + off] = 0;
    }
    if (tid < 48) g_t[2000 + tid] = 0.f;
  }
}

// ---- kcWh^T via MFMA (A from f32 kc_h on the fly) + fused t = kcWh@a2 ----
__global__ __launch_bounds__(256) void kc_mfma_kernel(
    const float* __restrict__ kc_h, const float* __restrict__ a) {
  __shared__ float tred[4][4][4];
  int tid = threadIdx.x, lane = tid & 63, w = tid >> 6;
  int r = lane & 15, g = lane >> 4;
  int j0 = blockIdx.x * 16;
  f32x4 acc[4] = {{0.f,0.f,0.f,0.f},{0.f,0.f,0.f,0.f},
                  {0.f,0.f,0.f,0.f},{0.f,0.f,0.f,0.f}};
  for (int kk = 0; kk < 8; ++kk) {
    int k = kk * 32 + g * 8;
    const float* src = kc_h + (size_t)(j0 + r) * 256 + k;
    float4 x0 = *(const float4*)src, x1 = *(const float4*)(src + 4);
    short8 af = {(short)f2bf(x0.x), (short)f2bf(x0.y), (short)f2bf(x0.z),
                 (short)f2bf(x0.w), (short)f2bf(x1.x), (short)f2bf(x1.y),
                 (short)f2bf(x1.z), (short)f2bf(x1.w)};
#pragma unroll
    for (int n = 0; n < 4; ++n) {
      short8 bf = *(const short8*)(g_W1T_pk + ((size_t)(w * 4 + n) * 8 + kk) *
                                                  512 + lane * 8);
      acc[n] = __builtin_amdgcn_mfma_f32_16x16x32_bf16(af, bf, acc[n], 0, 0, 0);
    }
  }
  int j = j0 + g * 4;
  int kt = j >> 5, lsub = ((j >> 3) & 3) * 16 + r, sub = (g & 1) * 4;
#pragma unroll
  for (int n = 0; n < 4; ++n) {
    int ct = w * 4 + n;
    ushort4 o;
    o.x = f2bf(acc[n][0]); o.y = f2bf(acc[n][1]);
    o.z = f2bf(acc[n][2]); o.w = f2bf(acc[n][3]);
    *reinterpret_cast<ushort4*>(
        g_kcWh_pk + ((size_t)ct * 64 + kt) * 512 + lsub * 8 + sub) = o;
  }
  float a2v[4];
#pragma unroll
  for (int n = 0; n < 4; ++n) a2v[n] = a[256 + w * 64 + n * 16 + r];
  float tp[4];
#pragma unroll
  for (int q = 0; q < 4; ++q)
    tp[q] = acc[0][q] * a2v[0] + acc[1][q] * a2v[1] + acc[2][q] * a2v[2] +
            acc[3][q] * a2v[3];
#pragma unroll
  for (int off = 1; off < 16; off <<= 1)
#pragma unroll
    for (int q = 0; q < 4; ++q) tp[q] += __shfl_xor(tp[q], off, 64);
  if (r == 0)
#pragma unroll
    for (int q = 0; q < 4; ++q) tred[w][g][q] = tp[q];
  __syncthreads();
  if (tid < 16)
    g_t[j0 + tid] = tred[0][tid >> 2][tid & 3] + tred[1][tid >> 2][tid & 3] +
                    tred[2][tid >> 2][tid & 3] + tred[3][tid >> 2][tid & 3];
}

// ---- main: 32 rows/block; inline-adj P-gen pipeline + 3 MFMA GEMMs ----
#define PSTR 136   // p_s row stride (shorts), 16B-aligned rows
#define FST 536    // feat row stride (shorts)
__global__ __launch_bounds__(512, 4) void main_kernel(
    const float* __restrict__ exh, const int* __restrict__ adj,
    const float* __restrict__ rd_b, float* __restrict__ out) {
  __shared__ __align__(16) unsigned char smem[41984];
  __shared__ float ds_part[8][32];
  __shared__ float red32[32];
  float* t_s = (float*)smem;                                   // 8192 B
  unsigned short* p_s = (unsigned short*)(smem + 8192);        // [2][32][136]
  unsigned short* exh_pk_s = (unsigned short*)(smem + 25600);  // [2][4096]
  unsigned short* feat_s = (unsigned short*)smem;              // [32][536] late

  int tid = threadIdx.x, w = tid >> 6, lane = tid & 63;
  int r = lane & 15, g = lane >> 4;
  int i0 = blockIdx.x * 32;
  int mh = w >> 2;  // gen row-half
  int kw = w & 3;   // gen kk sub-index

  // ---- phase 0: t_s, exh fragment staging, s = exh·w1a1 ----
  ((float4*)t_s)[tid] = ((const float4*)g_t)[tid];
  {
    const float* wsrc = g_w1a1 + w * 32 + g * 8;
    float4 w0 = *(const float4*)wsrc, w1 = *(const float4*)(wsrc + 4);
    float sp[2];
#pragma unroll
    for (int m = 0; m < 2; ++m) {
      int row = i0 + m * 16 + r; row = row < N_E ? row : N_E - 1;
      const float* xsrc = exh + (size_t)row * 256 + w * 32 + g * 8;
      float4 x0 = *(const float4*)xsrc, x1 = *(const float4*)(xsrc + 4);
      unsigned short* dst = exh_pk_s + m * 4096 + w * 512 + lane * 8;
      cvt_store4(x0, dst); cvt_store4(x1, dst + 4);
      sp[m] = x0.x * w0.x + x0.y * w0.y + x0.z * w0.z + x0.w * w0.w +
              x1.x * w1.x + x1.y * w1.y + x1.z * w1.z + x1.w * w1.w;
      sp[m] += __shfl_xor(sp[m], 16, 64);
      sp[m] += __shfl_xor(sp[m], 32, 64);
    }
    if (lane < 16) { ds_part[w][lane] = sp[0]; ds_part[w][16 + lane] = sp[1]; }
  }
  __syncthreads();
  if (tid < 32) {
    float sv = 0.f;
#pragma unroll
    for (int ww = 0; ww < 8; ++ww) sv += ds_part[ww][tid];
    red32[tid] = sv;
  }
  __syncthreads();
  float sv = red32[mh * 16 + r];
  int grow = i0 + mh * 16 + r; grow = grow < N_E ? grow : N_E - 1;
  const int* arow = adj + (size_t)grow * N_KC;

  f32x4 accP[2][2] = {{{0.f,0.f,0.f,0.f},{0.f,0.f,0.f,0.f}},
                      {{0.f,0.f,0.f,0.f},{0.f,0.f,0.f,0.f}}};
  float dsum = 0.f;

  // gen: wave (mh,kw) produces P rows [mh*16,mh*16+16) cols of kk=c*4+kw
  auto gen = [&](int c) {
    int kk = c * 4 + kw;
    int c0 = kk * 32 + g * 8;
    int4 pk = {0, 0, 0, 0};
    if (kk < 63 && c0 < N_KC) {
      int4 a0 = *(const int4*)(arow + c0);
      int4 a1 = *(const int4*)(arow + c0 + 4);
      float4 t0 = *(const float4*)(t_s + c0);
      float4 t1 = *(const float4*)(t_s + c0 + 4);
      float tv[8] = {t0.x, t0.y, t0.z, t0.w, t1.x, t1.y, t1.z, t1.w};
      int av[8] = {a0.x, a0.y, a0.z, a0.w, a1.x, a1.y, a1.z, a1.w};
      unsigned ub[8];
#pragma unroll
      for (int j = 0; j < 8; ++j) {
        float x = sv + tv[j];
        float lx = fmaxf(x, ALPHA * x);
        float pv = (av[j] > 0) ? __expf(lx) : 0.f;
        dsum += pv;
        ub[j] = __float_as_uint(pv) + 0x8000u;
      }
      pk.x = (int)((ub[0] >> 16) | (ub[1] & 0xFFFF0000u));
      pk.y = (int)((ub[2] >> 16) | (ub[3] & 0xFFFF0000u));
      pk.z = (int)((ub[4] >> 16) | (ub[5] & 0xFFFF0000u));
      pk.w = (int)((ub[6] >> 16) | (ub[7] & 0xFFFF0000u));
    }
    *(int4*)(p_s + ((size_t)(c & 1) * 32 + mh * 16 + r) * PSTR + kw * 32 +
             g * 8) = pk;
  };

  auto mfma_chunk = [&](int c) {
    const unsigned short* pb = p_s + (size_t)(c & 1) * 32 * PSTR;
    const unsigned short* bb0 =
        g_kcWh_pk + ((size_t)(w * 2 + 0) * 64 + c * 4) * 512 + lane * 8;
    const unsigned short* bb1 =
        g_kcWh_pk + ((size_t)(w * 2 + 1) * 64 + c * 4) * 512 + lane * 8;
    short8 b0 = *(const short8*)bb0;
    short8 b1 = *(const short8*)bb1;
#pragma unroll
    for (int u = 0; u < 4; ++u) {
      short8 a0 = *(const short8*)(pb + (size_t)r * PSTR + u * 32 + g * 8);
      short8 a1 = *(const short8*)(pb + (size_t)(16 + r) * PSTR + u * 32 + g * 8);
      short8 nb0 = b0, nb1 = b1;
      if (u < 3) {
        nb0 = *(const short8*)(bb0 + (u + 1) * 512);
        nb1 = *(const short8*)(bb1 + (u + 1) * 512);
      }
      accP[0][0] = __builtin_amdgcn_mfma_f32_16x16x32_bf16(a0, b0, accP[0][0], 0, 0, 0);
      accP[1][0] = __builtin_amdgcn_mfma_f32_16x16x32_bf16(a1, b0, accP[1][0], 0, 0, 0);
      accP[0][1] = __builtin_amdgcn_mfma_f32_16x16x32_bf16(a0, b1, accP[0][1], 0, 0, 0);
      accP[1][1] = __builtin_amdgcn_mfma_f32_16x16x32_bf16(a1, b1, accP[1][1], 0, 0, 0);
      b0 = nb0; b1 = nb1;
    }
  };

  gen(0);
  __syncthreads();
  for (int c = 1; c < 16; ++c) {
    gen(c);
    mfma_chunk(c - 1);
    __syncthreads();
  }
  mfma_chunk(15);

  // denominator partials (wave covers only its row-half; zero the other)
  dsum += __shfl_xor(dsum, 16, 64);
  dsum += __shfl_xor(dsum, 32, 64);
  if (lane < 16) {
    ds_part[w][mh * 16 + lane] = dsum;
    ds_part[w][(1 - mh) * 16 + lane] = 0.f;
  }

  // ---- ex_Eh GEMM ----
  f32x4 accE[2][2] = {{{0.f,0.f,0.f,0.f},{0.f,0.f,0.f,0.f}},
                      {{0.f,0.f,0.f,0.f},{0.f,0.f,0.f,0.f}}};
#pragma unroll
  for (int kk = 0; kk < 8; ++kk) {
    short8 a0 = *(const short8*)(exh_pk_s + kk * 512 + lane * 8);
    short8 a1 = *(const short8*)(exh_pk_s + 4096 + kk * 512 + lane * 8);
#pragma unroll
    for (int n = 0; n < 2; ++n) {
      short8 bf = *(const short8*)(g_ET_pk + ((size_t)(w * 2 + n) * 8 + kk) *
                                                 512 + lane * 8);
      accE[0][n] = __builtin_amdgcn_mfma_f32_16x16x32_bf16(a0, bf, accE[0][n], 0, 0, 0);
      accE[1][n] = __builtin_amdgcn_mfma_f32_16x16x32_bf16(a1, bf, accE[1][n], 0, 0, 0);
    }
  }
  __syncthreads();
  if (tid < 32) {
    float s = 0.f;
#pragma unroll
    for (int ww = 0; ww < 8; ++ww) s += ds_part[ww][tid];
    red32[tid] = 1.f / fmaxf(s, 1e-30f);
  }
  __syncthreads();

  // ---- feat = [new_kc | new_kc * ex_Eh] (overwrites t_s/p_s/exh region) ----
  int c0e = w * 32;
#pragma unroll
  for (int m = 0; m < 2; ++m)
#pragma unroll
    for (int n = 0; n < 2; ++n) {
      int col = c0e + n * 16 + r;
#pragma unroll
      for (int q = 0; q < 4; ++q) {
        int row = m * 16 + g * 4 + q;
        float nk = accP[m][n][q] * red32[row];
        feat_s[(size_t)row * FST + col] = f2bf(nk);
        feat_s[(size_t)row * FST + 256 + col] = f2bf(nk * accE[m][n][q]);
      }
    }
  __syncthreads();

  // ---- epilogue GEMM: feat(32x512) @ rd_w^T + bias, ELU ----
  f32x4 accO[2][2] = {{{0.f,0.f,0.f,0.f},{0.f,0.f,0.f,0.f}},
                      {{0.f,0.f,0.f,0.f},{0.f,0.f,0.f,0.f}}};
#pragma unroll
  for (int kt = 0; kt < 16; ++kt) {
    int k = kt * 32 + g * 8;
    short8 a0 = *(const short8*)(feat_s + (size_t)r * FST + k);
    short8 a1 = *(const short8*)(feat_s + (size_t)(16 + r) * FST + k);
#pragma unroll
    for (int n = 0; n < 2; ++n) {
      short8 bf = *(const short8*)(g_rdw_pk + ((size_t)(w * 2 + n) * 16 + kt) *
                                                  512 + lane * 8);
      accO[0][n] = __builtin_amdgcn_mfma_f32_16x16x32_bf16(a0, bf, accO[0][n], 0, 0, 0);
      accO[1][n] = __builtin_amdgcn_mfma_f32_16x16x32_bf16(a1, bf, accO[1][n], 0, 0, 0);
    }
  }
#pragma unroll
  for (int m = 0; m < 2; ++m) {
    if (i0 + m * 16 >= N_E) continue;
#pragma unroll
    for (int n = 0; n < 2; ++n) {
      int col = c0e + n * 16 + r;
      float bias = rd_b[col];
#pragma unroll
      for (int q = 0; q < 4; ++q) {
        int row = i0 + m * 16 + g * 4 + q;
        float x = accO[m][n][q] + bias;
        float res = x > 0.f ? x : (__expf(x) - 1.f);
        out[(size_t)row * 256 + col] = res;
      }
    }
  }
}

extern "C" void kernel_launch(void* const* d_in, const int* in_sizes, int n_in,
                              void* d_out, int out_size, void* d_ws,
                              size_t ws_size, hipStream_t stream) {
  const float* exh  = (const float*)d_in[0];
  const float* kc_h = (const float*)d_in[1];
  const int*   adj  = (const int*)d_in[2];
  const float* W1   = (const float*)d_in[3];
  const float* E    = (const float*)d_in[4];
  const float* a    = (const float*)d_in[5];
  const float* rd_w = (const float*)d_in[6];
  const float* rd_b = (const float*)d_in[7];
  float* out = (float*)d_out;

  prep_kernel<<<66, 256, 0, stream>>>(W1, E, a, rd_w);
  kc_mfma_kernel<<<N_KC / 16, 256, 0, stream>>>(kc_h, a);
  main_kernel<<<(N_E + 31) / 32, 512, 0, stream>>>(exh, adj, rd_b, out);
}